// Round 2
// baseline (529.259 us; speedup 1.0000x reference)
//
#include <hip/hip_runtime.h>
#include <stdint.h>

typedef float f32x16 __attribute__((ext_vector_type(16)));

#define FP8_MAX_V 448.0f

// Pack 4 floats -> 4 OCP e4m3fn bytes, RNE, after reference-matching clip.
__device__ __forceinline__ uint32_t pack4_fp8(float a, float b, float c, float d) {
    a = fminf(fmaxf(a, -FP8_MAX_V), FP8_MAX_V);
    b = fminf(fmaxf(b, -FP8_MAX_V), FP8_MAX_V);
    c = fminf(fmaxf(c, -FP8_MAX_V), FP8_MAX_V);
    d = fminf(fmaxf(d, -FP8_MAX_V), FP8_MAX_V);
    int v = 0;
    v = __builtin_amdgcn_cvt_pk_fp8_f32(a, b, v, false);  // bytes 0,1
    v = __builtin_amdgcn_cvt_pk_fp8_f32(c, d, v, true);   // bytes 2,3
    return (uint32_t)v;
}

__global__ void quant_fp8_kernel(const float* __restrict__ in,
                                 uint32_t* __restrict__ out,
                                 const float* __restrict__ scale_ptr,
                                 long long n4) {
    const float s = scale_ptr[0];
    long long i = (long long)blockIdx.x * blockDim.x + threadIdx.x;
    const long long stride = (long long)gridDim.x * blockDim.x;
    const float4* in4 = (const float4*)in;
    for (; i < n4; i += stride) {
        float4 v = in4[i];
        out[i] = pack4_fp8(v.x / s, v.y / s, v.z / s, v.w / s);
    }
}

// Phase-pipelined fp8 GEMM: C[M,N] = (qA . qB^T) * outscale + bias
// BM=256, BN=128, BK=64 bytes. Ring-4 LDS (4 x 24 KiB slots: A 16K + B 8K).
// 8 waves = 4(M) x 2(N); per-wave output 64x64 via mfma_f32_32x32x16_fp8_fp8.
// Per tile: 2 phases {stage T+3 part; 8 ds_read_b64; barrier; 8 MFMA; barrier},
// counted vmcnt(6) once per tile (3 tiles / 9 loads in flight, never drain 0).
// LDS swizzle: 16B-chunk' = chunk ^ ((row>>1)&3), applied on the global source
// (global_load_lds dest must be linear) and on the ds_read column.
__global__ __launch_bounds__(512) void gemm_fp8_kernel(
    const uint8_t* __restrict__ qA,   // [M][K] fp8
    const uint8_t* __restrict__ qB,   // [N][K] fp8
    const float* __restrict__ bias,   // [N]
    const float* __restrict__ s_in_p,
    const float* __restrict__ s_w_p,
    float* __restrict__ C,            // [M][N] fp32
    int M, int N, int K) {
    extern __shared__ uint8_t lds[];  // 4 * 24576 = 98304 B

    const int tid = threadIdx.x;
    const int w   = tid >> 6;    // wave 0..7
    const int l   = tid & 63;
    const int wr  = w >> 1;      // 0..3  -> rows [wr*64, +64)
    const int wc  = w & 1;       // 0..1  -> cols [wc*64, +64)
    const int rl  = l & 31;
    const int hi8 = (l >> 5) << 3;
    const int s2  = (rl >> 1) & 3;

    // XCD-bijective block swizzle (nwg = 1792, 1792 % 8 == 0)
    const int cpx = gridDim.x >> 3;
    const int swz = ((int)blockIdx.x & 7) * cpx + ((int)blockIdx.x >> 3);
    const int tm  = swz & 15;    // M/256 = 16
    const int tn  = swz >> 4;    // N/128 = 112
    const int bm  = tm << 8;
    const int bn  = tn << 7;

    const float outscale = s_in_p[0] * s_w_p[0];
    const int NT = K >> 6;       // 64 K-tiles

    // per-lane swizzled column offsets for kk=0..3 (K=16 each)
    int colk[4];
#pragma unroll
    for (int kk = 0; kk < 4; ++kk) colk[kk] = ((kk ^ s2) << 4) | hi8;

    const int aRowOff = (wr * 64 + rl) * 64;            // + mi*2048 + colk[kk]
    const int bRowOff = 16384 + (wc * 64 + rl) * 64;    // + ni*2048 + colk[kk]

    f32x16 acc[2][2];
#pragma unroll
    for (int mi = 0; mi < 2; ++mi)
#pragma unroll
        for (int ni = 0; ni < 2; ++ni)
#pragma unroll
            for (int r = 0; r < 16; ++r) acc[mi][ni][r] = 0.f;

    // Staging: per thread, row = tid>>2 (0..127), 16B chunk = tid&3, source
    // chunk pre-swizzled. (row>>1)&3 is j-independent since j*128 % 4 rows == 0.
    const int strow   = tid >> 2;
    const int stchunk = (((tid & 3) ^ ((strow >> 1) & 3)) << 4);
    const uint8_t* srcA_t = qA + (size_t)(bm + strow) * K + stchunk;
    const uint8_t* srcB_t = qB + (size_t)(bn + strow) * K + stchunk;
    const int dstw = w << 10;   // wave-uniform LDS base piece (+ lane*16 by HW)

#define STAGE_A(SLOT, KB) do { \
    __builtin_amdgcn_global_load_lds( \
        (const __attribute__((address_space(1))) void*)(srcA_t + (KB)), \
        (__attribute__((address_space(3))) void*)(lds + (SLOT) * 24576 + dstw), 16, 0, 0); \
    __builtin_amdgcn_global_load_lds( \
        (const __attribute__((address_space(1))) void*)(srcA_t + (size_t)128 * K + (KB)), \
        (__attribute__((address_space(3))) void*)(lds + (SLOT) * 24576 + 8192 + dstw), 16, 0, 0); \
} while (0)

#define STAGE_B(SLOT, KB) do { \
    __builtin_amdgcn_global_load_lds( \
        (const __attribute__((address_space(1))) void*)(srcB_t + (KB)), \
        (__attribute__((address_space(3))) void*)(lds + (SLOT) * 24576 + 16384 + dstw), 16, 0, 0); \
} while (0)

    // Prologue: stage tiles 0,1,2 (order per tile: A,A,B), one-time full drain.
    STAGE_A(0, 0);   STAGE_B(0, 0);
    STAGE_A(1, 64);  STAGE_B(1, 64);
    STAGE_A(2, 128); STAGE_B(2, 128);
    __syncthreads();

    long a[2][2], b[2][2];
    for (int T = 0; T < NT; ++T) {
        const int slot = T & 3;
        const int sb   = slot * 24576;
        const int Tp   = T + 3;
        const int kbp  = (Tp < NT) ? (Tp << 6) : 0;  // clamp: writes dead slot
        const int slotp = Tp & 3;

        // ---------- phase 0: kk 0,1 ----------
        STAGE_A(slotp, kbp);
#pragma unroll
        for (int mi = 0; mi < 2; ++mi)
#pragma unroll
            for (int kk = 0; kk < 2; ++kk)
                a[mi][kk] = *(const long*)(lds + sb + aRowOff + mi * 2048 + colk[kk]);
#pragma unroll
        for (int ni = 0; ni < 2; ++ni)
#pragma unroll
            for (int kk = 0; kk < 2; ++kk)
                b[ni][kk] = *(const long*)(lds + sb + bRowOff + ni * 2048 + colk[kk]);
        __builtin_amdgcn_s_barrier();
        __builtin_amdgcn_s_setprio(1);
#pragma unroll
        for (int kk = 0; kk < 2; ++kk)
#pragma unroll
            for (int mi = 0; mi < 2; ++mi)
#pragma unroll
                for (int ni = 0; ni < 2; ++ni)
                    acc[mi][ni] = __builtin_amdgcn_mfma_f32_32x32x16_fp8_fp8(
                        a[mi][kk], b[ni][kk], acc[mi][ni], 0, 0, 0);
        __builtin_amdgcn_s_setprio(0);
        __builtin_amdgcn_s_barrier();

        // ---------- phase 1: kk 2,3 ----------
        STAGE_B(slotp, kbp);
#pragma unroll
        for (int mi = 0; mi < 2; ++mi)
#pragma unroll
            for (int kk = 0; kk < 2; ++kk)
                a[mi][kk] = *(const long*)(lds + sb + aRowOff + mi * 2048 + colk[kk + 2]);
#pragma unroll
        for (int ni = 0; ni < 2; ++ni)
#pragma unroll
            for (int kk = 0; kk < 2; ++kk)
                b[ni][kk] = *(const long*)(lds + sb + bRowOff + ni * 2048 + colk[kk + 2]);
        __builtin_amdgcn_s_barrier();
        __builtin_amdgcn_s_setprio(1);
#pragma unroll
        for (int kk = 0; kk < 2; ++kk)
#pragma unroll
            for (int mi = 0; mi < 2; ++mi)
#pragma unroll
                for (int ni = 0; ni < 2; ++ni)
                    acc[mi][ni] = __builtin_amdgcn_mfma_f32_32x32x16_fp8_fp8(
                        a[mi][kk], b[ni][kk], acc[mi][ni], 0, 0, 0);
        __builtin_amdgcn_s_setprio(0);
        // tile T+1's staging (issued during T-2) must be landed; keep
        // tiles T+2, T+3 stagings (6 loads) in flight — never drain to 0.
        asm volatile("s_waitcnt vmcnt(6)" ::: "memory");
        __builtin_amdgcn_s_barrier();
    }

    // Epilogue. C/D layout (32x32): col = lane&31, row = (r&3)+8*(r>>2)+4*(l>>5).
    const int crow0 = bm + wr * 64 + ((l >> 5) << 2);
    const int ccol0 = bn + wc * 64 + rl;
    const float bv0 = bias[ccol0];
    const float bv1 = bias[ccol0 + 32];
#pragma unroll
    for (int mi = 0; mi < 2; ++mi)
#pragma unroll
        for (int ni = 0; ni < 2; ++ni) {
            const float bv = ni ? bv1 : bv0;
            const int col = ccol0 + ni * 32;
#pragma unroll
            for (int r = 0; r < 16; ++r) {
                const int row = crow0 + mi * 32 + (r & 3) + ((r >> 2) << 3);
                C[(size_t)row * N + col] = acc[mi][ni][r] * outscale + bv;
            }
        }
#undef STAGE_A
#undef STAGE_B
}

extern "C" void kernel_launch(void* const* d_in, const int* in_sizes, int n_in,
                              void* d_out, int out_size, void* d_ws, size_t ws_size,
                              hipStream_t stream) {
    const float* x    = (const float*)d_in[0];
    const float* wt   = (const float*)d_in[1];
    const float* bias = (const float*)d_in[2];
    const float* s_in = (const float*)d_in[3];
    const float* s_w  = (const float*)d_in[4];
    float* out = (float*)d_out;

    const long long xe = in_sizes[0];            // M*K
    const long long we = in_sizes[1];            // N*K
    const int N = in_sizes[2];
    const int K = (int)(we / N);
    const int M = (int)(xe / K);

    uint8_t* qx = (uint8_t*)d_ws;                // M*K fp8
    uint8_t* qw = qx + xe;                       // N*K fp8

    quant_fp8_kernel<<<2048, 256, 0, stream>>>(x,  (uint32_t*)qx, s_in, xe >> 2);
    quant_fp8_kernel<<<2048, 256, 0, stream>>>(wt, (uint32_t*)qw, s_w,  we >> 2);

    dim3 grid((N / 128) * (M / 256));            // 112*16 = 1792 = 7 per CU
    gemm_fp8_kernel<<<grid, 512, 98304, stream>>>(qx, qw, bias, s_in, s_w, out,
                                                  M, N, K);
}